// Round 6
// baseline (586.902 us; speedup 1.0000x reference)
//
#include <hip/hip_runtime.h>
#include <stdint.h>

#define Bb 8
#define Tt 2048
#define Cc 512

typedef __attribute__((ext_vector_type(8))) short short8;
typedef __attribute__((ext_vector_type(4))) short short4v;
typedef __attribute__((ext_vector_type(4))) float f32x4;

#define SZE ((size_t)Bb * Tt * Cc)

__device__ __forceinline__ float b2f(short s) {
  unsigned int x = ((unsigned int)(unsigned short)s) << 16;
  return __builtin_bit_cast(float, x);
}
__device__ __forceinline__ short f2b(float f) {
  unsigned int x = __builtin_bit_cast(unsigned int, f);
  x += 0x7fffu + ((x >> 16) & 1u);   // round-to-nearest-even
  return (short)(x >> 16);
}

// Async global->LDS DMA, 16B per lane. LDS dest is wave-uniform base +
// lane*16 [m104/m108]; global src is per-lane (inverse-swizzled) [m173/m201].
__device__ __forceinline__ void gload16(const void* g, void* l) {
  __builtin_amdgcn_global_load_lds(
      (const __attribute__((address_space(1))) void*)g,
      (__attribute__((address_space(3))) void*)l, 16, 0, 0);
}

// ---------------------------------------------------------------------------
// GEMM: C[m,n] = epilogue( sum_k A[m,k] * B[n,k] )   (B row-major N x K, bf16)
// MODE 0: A fp32 (z-sel Av/Av2),     C bf16, +bias[z*N+n]          (pointwise)
// MODE 1: A bf16 dir-sel, B dir-sel, C bf16 dir-sel                (VWT = W3*V)
// MODE 2: A bf16 dir-sel, B dir-sel, C fp32 = acc/sum + b3 + x     (PV+out)
// MODE 4: scores fused: C=exp(val*scale) -> E (bf16) AND E^T, plus atomic
//         per-row / per-col exp-sum accumulation (softmax denominators).
// Staging: global_load_lds dwordx4 (m93->m97 ladder step, +69%). LDS layout
// chunk(m,kc) at index kc*128+(m^kc) (conflict-free b128 reads); DMA writes
// linearly at chunk d, so the per-lane SOURCE row is (d&127)^(d>>7) (inverse
// swizzle; XOR is an involution). MODE0 keeps fp32 A reg-staged (no DMA cvt).
// 128x128 tile, BK=64, 4 waves 2x2, wave tile 64x64 via 4x4 MFMA 16x16x32.
// XCD swizzle (gy%8==0 only): each XCD owns a contiguous y-chunk.
// ---------------------------------------------------------------------------
template<int MODE>
__global__ __launch_bounds__(256, 2)
void gemm_bt(const void* __restrict__ Av, const void* __restrict__ Av2,
             const void* __restrict__ Bv, const void* __restrict__ Bv2,
             void* __restrict__ Cv, void* __restrict__ Cv2,
             const float* __restrict__ bias,
             const float* __restrict__ resid, const float* __restrict__ resid2,
             short* __restrict__ ET, float* __restrict__ sumR, float* __restrict__ sumC,
             int M, int N, int K,
             long long sA, long long sB, long long sC, float scale)
{
  __shared__ __align__(16) short ldsA[8 * 128 * 8];
  __shared__ __align__(16) short ldsB[8 * 128 * 8];
  const int tid  = threadIdx.x;
  const int lane = tid & 63;

  // ---- bijective XCD swizzle (active when gridDim.y % 8 == 0) ----
  int bxi = blockIdx.x, byi = blockIdx.y, bzi = blockIdx.z;
  const int gx = gridDim.x, gy = gridDim.y;
  if ((gy & 7) == 0) {
    int l = bxi + gx * (byi + gy * bzi);
    const int xcd = l & 7;
    int loc = l >> 3;
    const int ych = gy >> 3;
    bxi = loc % gx;  loc /= gx;
    byi = xcd * ych + (loc % ych);
    bzi = loc / ych;
  }

  const int bm = byi * 128;
  const int bn = bxi * 128;
  int dir = 0, zz = bzi;
  if constexpr (MODE == 1 || MODE == 2) { dir = bzi >> 3; zz = bzi & 7; }
  const long long zoA = (long long)zz * sA;
  const long long zoB = (long long)zz * sB;
  const long long zoC = (long long)zz * sC;
  const void* Ause = Av;
  const void* Buse = Bv;
  void* Cuse = Cv;
  if constexpr (MODE == 0) {
    if (zz) Ause = Av2;
  }
  if constexpr (MODE == 1 || MODE == 2) {
    if (dir) { Ause = Av2; Buse = Bv2; Cuse = Cv2; }
  }

  const int wv = tid >> 6;
  const int wm = (wv >> 1) << 6;
  const int wn = (wv & 1) << 6;
  const int wvb = wv << 6;                   // wave chunk base for DMA staging

  f32x4 zero4 = {0.f, 0.f, 0.f, 0.f};
  f32x4 acc[4][4];
#pragma unroll
  for (int i = 0; i < 4; ++i)
#pragma unroll
    for (int j = 0; j < 4; ++j)
      acc[i][j] = zero4;

  const int sm  = tid >> 3;  // 0..31  (MODE0 fp32-A staging)
  const int skc = tid & 7;   // 0..7

  for (int k0 = 0; k0 < K; k0 += 64) {
    if constexpr (MODE == 0) {
      // fp32 A: reg-staged convert + swizzled ds_write
#pragma unroll
      for (int r = 0; r < 4; ++r) {
        const int m = r * 32 + sm;
        const float* ap = (const float*)Ause + zoA + (size_t)(bm + m) * K + k0 + skc * 8;
        float4 f0 = *(const float4*)ap;
        float4 f1 = *(const float4*)(ap + 4);
        short8 av;
        av[0] = f2b(f0.x); av[1] = f2b(f0.y); av[2] = f2b(f0.z); av[3] = f2b(f0.w);
        av[4] = f2b(f1.x); av[5] = f2b(f1.y); av[6] = f2b(f1.z); av[7] = f2b(f1.w);
        *(short8*)&ldsA[((skc << 7) + (m ^ skc)) << 3] = av;
      }
      // bf16 B: DMA
#pragma unroll
      for (int q = 0; q < 4; ++q) {
        const int d  = q * 256 + wvb + lane;
        const int kc = d >> 7;
        const int mm = (d & 127) ^ kc;
        gload16((const short*)Buse + zoB + (size_t)(bn + mm) * K + k0 + kc * 8,
                &ldsB[(size_t)(q * 256 + wvb) * 8]);
      }
    } else {
#pragma unroll
      for (int q = 0; q < 4; ++q) {
        const int d  = q * 256 + wvb + lane;
        const int kc = d >> 7;
        const int mm = (d & 127) ^ kc;
        const size_t ko = (size_t)k0 + kc * 8;
        gload16((const short*)Ause + zoA + (size_t)(bm + mm) * K + ko,
                &ldsA[(size_t)(q * 256 + wvb) * 8]);
        gload16((const short*)Buse + zoB + (size_t)(bn + mm) * K + ko,
                &ldsB[(size_t)(q * 256 + wvb) * 8]);
      }
    }
    __syncthreads();
#pragma unroll
    for (int kk = 0; kk < 2; ++kk) {
      const int kcr = (kk << 2) + (lane >> 4);
      short8 af[4], bfv[4];
#pragma unroll
      for (int i = 0; i < 4; ++i) {
        const int ma = wm + i * 16 + (lane & 15);
        const int nb = wn + i * 16 + (lane & 15);
        af[i]  = *(const short8*)&ldsA[((kcr << 7) + (ma ^ kcr)) << 3];
        bfv[i] = *(const short8*)&ldsB[((kcr << 7) + (nb ^ kcr)) << 3];
      }
#pragma unroll
      for (int i = 0; i < 4; ++i)
#pragma unroll
        for (int j = 0; j < 4; ++j)
          acc[i][j] = __builtin_amdgcn_mfma_f32_16x16x32_bf16(af[i], bfv[j], acc[i][j], 0, 0, 0);
    }
    __syncthreads();
  }

  // C/D layout: col = lane&15, row = (lane>>4)*4 + reg  [measured m89/m91]
  if constexpr (MODE == 4) {
    // ---- exp transform (max-free softmax numerator) ----
#pragma unroll
    for (int i = 0; i < 4; ++i)
#pragma unroll
      for (int j = 0; j < 4; ++j)
#pragma unroll
        for (int r = 0; r < 4; ++r)
          acc[i][j][r] = __expf(acc[i][j][r] * scale);

    // ---- write E (row-major) and E^T ----
#pragma unroll
    for (int i = 0; i < 4; ++i) {
      const int row0 = bm + wm + i * 16 + ((lane >> 4) << 2);
#pragma unroll
      for (int j = 0; j < 4; ++j) {
        const int n = bn + wn + j * 16 + (lane & 15);
        short4v t;
#pragma unroll
        for (int r = 0; r < 4; ++r) t[r] = f2b(acc[i][j][r]);
#pragma unroll
        for (int r = 0; r < 4; ++r)
          ((short*)Cv)[zoC + (size_t)(row0 + r) * N + n] = t[r];
        *(short4v*)(ET + zoC + (size_t)n * M + row0) = t;
      }
    }
    // ---- row sums (dir0 denominators) ----
#pragma unroll
    for (int i = 0; i < 4; ++i) {
      const int row0 = bm + wm + i * 16 + ((lane >> 4) << 2);
#pragma unroll
      for (int r = 0; r < 4; ++r) {
        float p = acc[i][0][r] + acc[i][1][r] + acc[i][2][r] + acc[i][3][r];
#pragma unroll
        for (int o = 1; o < 16; o <<= 1) p += __shfl_xor(p, o, 64);
        if ((lane & 15) == 0)
          unsafeAtomicAdd(&sumR[(size_t)zz * M + row0 + r], p);
      }
    }
    // ---- col sums (dir1 denominators) ----
#pragma unroll
    for (int j = 0; j < 4; ++j) {
      const int n = bn + wn + j * 16 + (lane & 15);
      float q = 0.f;
#pragma unroll
      for (int i = 0; i < 4; ++i)
#pragma unroll
        for (int r = 0; r < 4; ++r) q += acc[i][j][r];
      q += __shfl_xor(q, 16, 64);
      q += __shfl_xor(q, 32, 64);
      if (lane < 16)
        unsafeAtomicAdd(&sumC[(size_t)zz * N + n], q);
    }
  } else if constexpr (MODE == 2) {
    const float* sums = dir ? sumC : sumR;
    const float* xr   = dir ? resid2 : resid;
#pragma unroll
    for (int i = 0; i < 4; ++i) {
      const int row0 = bm + wm + i * 16 + ((lane >> 4) << 2);
#pragma unroll
      for (int r = 0; r < 4; ++r) {
        const float iv = 1.0f / sums[(size_t)zz * M + row0 + r];
#pragma unroll
        for (int j = 0; j < 4; ++j) {
          const int n = bn + wn + j * 16 + (lane & 15);
          const size_t off = zoC + (size_t)(row0 + r) * N + n;
          ((float*)Cuse)[off] = acc[i][j][r] * iv + bias[dir * N + n] + xr[off];
        }
      }
    }
  } else {
#pragma unroll
    for (int i = 0; i < 4; ++i) {
      const int row0 = bm + wm + i * 16 + ((lane >> 4) << 2);
#pragma unroll
      for (int j = 0; j < 4; ++j) {
        const int n = bn + wn + j * 16 + (lane & 15);
        float badd = 0.f;
        if (MODE == 0) badd = bias[(size_t)zz * N + n];
#pragma unroll
        for (int r = 0; r < 4; ++r) {
          float val = acc[i][j][r];
          if (MODE == 0) val += badd;
          ((short*)Cuse)[zoC + (size_t)(row0 + r) * N + n] = f2b(val);
        }
      }
    }
  }
  (void)resid; (void)resid2; (void)ET; (void)sumR; (void)sumC;
  (void)bias; (void)scale; (void)Cuse; (void)M;
}

// ---------------------------------------------------------------------------
// One-shot weight/bias packing + softmax-denominator zeroing.
// Wl=[lp1_w1;lp2_w1], Wr=[rp1_w1;rp2_w1], W3l|W3r, BL=[lp1_b1;lp2_b1], BR,
// B3=[lp3_b;rp3_b], SUM = sumR(16384) ++ sumC(16384) zeroed.
// ---------------------------------------------------------------------------
__global__ __launch_bounds__(256)
void pack_all(const float* __restrict__ lw1a, const float* __restrict__ lw1b,
              const float* __restrict__ rw1a, const float* __restrict__ rw1b,
              const float* __restrict__ w3lf, const float* __restrict__ w3rf,
              const float* __restrict__ lb1a, const float* __restrict__ lb1b,
              const float* __restrict__ rb1a, const float* __restrict__ rb1b,
              const float* __restrict__ b3l, const float* __restrict__ b3r,
              short* __restrict__ Wl, short* __restrict__ Wr,
              short* __restrict__ W3l, short* __restrict__ W3r,
              float* __restrict__ BL, float* __restrict__ BR,
              float* __restrict__ B3, float* __restrict__ SUM)
{
  const int i = blockIdx.x * 256 + threadIdx.x;
  if (i < 524288) {
    Wl[i] = f2b(i < 262144 ? lw1a[i] : lw1b[i - 262144]);
  } else if (i < 1048576) {
    const int j = i - 524288;
    Wr[j] = f2b(j < 262144 ? rw1a[j] : rw1b[j - 262144]);
  } else if (i < 1310720) {
    W3l[i - 1048576] = f2b(w3lf[i - 1048576]);
  } else if (i < 1572864) {
    W3r[i - 1310720] = f2b(w3rf[i - 1310720]);
  } else if (i < 1573888) {
    const int j = i - 1572864;
    BL[j] = j < 512 ? lb1a[j] : lb1b[j - 512];
  } else if (i < 1574912) {
    const int j = i - 1573888;
    BR[j] = j < 512 ? rb1a[j] : rb1b[j - 512];
  } else if (i < 1575936) {
    const int j = i - 1574912;
    B3[j] = j < 512 ? b3l[j] : b3r[j - 512];
  } else if (i < 1608704) {
    SUM[i - 1575936] = 0.f;
  }
}

// ---------------------------------------------------------------------------
// Depthwise conv k=3 pad=1 over T; 4 outputs in one launch (blockIdx.y):
//   y=0: H_l cols[0,512)   w=lp1 -> Ql   y=1: H_r cols[0,512)   w=rp1 -> Qr
//   y=2: H_l cols[512,1024) w=lp2 -> Vl  y=3: H_r cols[512,1024) w=rp2 -> Vr
// H row stride 1024 (fused proj output). All outputs row-major (B*T, 512).
// ---------------------------------------------------------------------------
__global__ __launch_bounds__(256)
void dw_kernel(const short* __restrict__ H, long long hStride,
               const float* __restrict__ w2a, const float* __restrict__ w2b,
               const float* __restrict__ w2c, const float* __restrict__ w2d,
               const float* __restrict__ b2a, const float* __restrict__ b2b,
               const float* __restrict__ b2c, const float* __restrict__ b2d,
               short* __restrict__ out)
{
  const int y = blockIdx.y;
  const short* Hd = H + (size_t)(y & 1) * hStride;
  const float* w2 = (y == 0) ? w2a : (y == 1) ? w2b : (y == 2) ? w2c : w2d;
  const float* b2 = (y == 0) ? b2a : (y == 1) ? b2b : (y == 2) ? b2c : b2d;
  const int colOff = (y & 2) ? 512 : 0;
  short* outd = out + (size_t)y * SZE;

  const int idx = blockIdx.x * 256 + threadIdx.x;   // over B*T*512/8
  const int c8 = idx & 63;
  const int bt = idx >> 6;
  const int t  = bt & (Tt - 1);
  const int c  = c8 << 3;
  const short* base = Hd + (size_t)bt * 1024 + colOff + c;
  short8 zv = {0, 0, 0, 0, 0, 0, 0, 0};
  short8 hm = zv, hp = zv;
  short8 h0 = *(const short8*)base;
  if (t > 0)      hm = *(const short8*)(base - 1024);
  if (t < Tt - 1) hp = *(const short8*)(base + 1024);
  short8 o;
#pragma unroll
  for (int j = 0; j < 8; ++j) {
    const int cj = c + j;
    float val = b2f(hm[j]) * w2[cj * 3 + 0]
              + b2f(h0[j]) * w2[cj * 3 + 1]
              + b2f(hp[j]) * w2[cj * 3 + 2]
              + b2[cj];
    o[j] = f2b(val);
  }
  *(short8*)(outd + (size_t)bt * Cc + c) = o;
}

// ---------------------------------------------------------------------------
extern "C" void kernel_launch(void* const* d_in, const int* in_sizes, int n_in,
                              void* d_out, int out_size, void* d_ws, size_t ws_size,
                              hipStream_t stream)
{
  const float* x_l    = (const float*)d_in[0];
  const float* x_r    = (const float*)d_in[1];
  const float* lp1_w1 = (const float*)d_in[2];
  const float* lp1_b1 = (const float*)d_in[3];
  const float* lp1_w2 = (const float*)d_in[4];
  const float* lp1_b2 = (const float*)d_in[5];
  const float* rp1_w1 = (const float*)d_in[6];
  const float* rp1_b1 = (const float*)d_in[7];
  const float* rp1_w2 = (const float*)d_in[8];
  const float* rp1_b2 = (const float*)d_in[9];
  const float* lp2_w1 = (const float*)d_in[10];
  const float* lp2_b1 = (const float*)d_in[11];
  const float* lp2_w2 = (const float*)d_in[12];
  const float* lp2_b2 = (const float*)d_in[13];
  const float* rp2_w1 = (const float*)d_in[14];
  const float* rp2_b1 = (const float*)d_in[15];
  const float* rp2_w2 = (const float*)d_in[16];
  const float* rp2_b2 = (const float*)d_in[17];
  const float* lp3_w  = (const float*)d_in[18];
  const float* lp3_b  = (const float*)d_in[19];
  const float* rp3_w  = (const float*)d_in[20];
  const float* rp3_b  = (const float*)d_in[21];

  short* ws = (short*)d_ws;
  const size_t SZ = SZE;                     // 8,388,608 bf16 elems (16.78 MB)
  short* Ql   = ws;                          // slot0; later VWT0
  short* Qr   = ws + SZ;                     // slot1; later VWT1
  short* Vl   = ws + 2 * SZ;                 // slot2
  short* Vr   = ws + 3 * SZ;                 // slot3
  short* E    = ws + 4 * SZ;                 // [4,8)SZ; H aliases this region
  short* ETb  = ws + 8 * SZ;                 // [8,12)SZ
  short* H    = E;
  short* VWT0 = Ql;                          // Q dead after QK^T
  short* VWT1 = Qr;

  const size_t W_PAIR = 524288, W_SING = 262144;
  short* Wl  = ws + 12 * SZ;
  short* Wr  = Wl + W_PAIR;
  short* W3l = Wr + W_PAIR;
  short* W3r = W3l + W_SING;
  float* BL  = (float*)(W3r + W_SING);
  float* BR  = BL + 1024;
  float* B3  = BR + 1024;
  float* SUMR = B3 + 1024;                   // 16384 floats (dir0 row sums)
  float* SUMC = SUMR + 16384;                // 16384 floats (dir1 = col sums)

  const float scale = 0.04419417382415922f;  // 512^-0.5
  const int MT = Bb * Tt;                    // 16384
  const long long sQ = (long long)Tt * Cc;   // 1,048,576
  const long long sS = (long long)Tt * Tt;   // 4,194,304

  dim3 blk(256);

  // ---- phase 0: pack weights + zero softmax denominators ----
  pack_all<<<6284, blk, 0, stream>>>(lp1_w1, lp2_w1, rp1_w1, rp2_w1, lp3_w, rp3_w,
                                     lp1_b1, lp2_b1, rp1_b1, rp2_b1, lp3_b, rp3_b,
                                     Wl, Wr, W3l, W3r, BL, BR, B3, SUMR);

  // ---- phase 1: fused pointwise proj (N=1024, both dirs z=2) -> dw convs ----
  gemm_bt<0><<<dim3(8, 128, 2), blk, 0, stream>>>(
      x_l, x_r, Wl, nullptr, H, nullptr, BL, nullptr, nullptr,
      nullptr, nullptr, nullptr,
      MT, 1024, Cc, 0, (long long)W_PAIR, (long long)(2 * SZ), 1.f);
  dw_kernel<<<dim3(4096, 4), blk, 0, stream>>>(
      H, (long long)(2 * SZ),
      lp1_w2, rp1_w2, lp2_w2, rp2_w2,
      lp1_b2, rp1_b2, lp2_b2, rp2_b2, Ql);

  // ---- phase 2a: single fused QK^T -> exp -> E, E^T, row/col sums ----
  gemm_bt<4><<<dim3(Tt / 128, Tt / 128, Bb), blk, 0, stream>>>(
      Ql, nullptr, Qr, nullptr, E, nullptr, nullptr, nullptr, nullptr,
      ETb, SUMR, SUMC,
      Tt, Tt, Cc, sQ, sQ, sS, scale);

  // ---- phase 2b: VWT[d,s] = sum_c W3[d,c] V[s,c]  (z=16: dir,batch) ----
  // dir0 uses V_r (feeds out_l), dir1 uses V_l. Overwrites dead Q slots.
  gemm_bt<1><<<dim3(Tt / 128, 4, 2 * Bb), blk, 0, stream>>>(
      W3l, W3r, Vr, Vl, VWT0, VWT1, nullptr, nullptr, nullptr,
      nullptr, nullptr, nullptr,
      512, Tt, Cc, 0, sQ, (long long)(512 * Tt), 1.f);

  // ---- phase 3: PV + epilogue = out (z=16): C = E*VWT/sum + b3 + x ----
  gemm_bt<2><<<dim3(Cc / 128, Tt / 128, 2 * Bb), blk, 0, stream>>>(
      E, ETb, VWT0, VWT1, d_out, (float*)d_out + SZ, B3, x_l, x_r,
      nullptr, SUMR, SUMC,
      Tt, Cc, Tt, sS, (long long)(512 * Tt), sQ, 1.f);

  (void)in_sizes; (void)n_in; (void)out_size; (void)ws_size;
}

// Round 7
// 428.465 us; speedup vs baseline: 1.3698x; 1.3698x over previous
//
#include <hip/hip_runtime.h>
#include <stdint.h>

#define Bb 8
#define Tt 2048
#define Cc 512

typedef __attribute__((ext_vector_type(8))) short short8;
typedef __attribute__((ext_vector_type(4))) short short4v;
typedef __attribute__((ext_vector_type(4))) float f32x4;

#define SZE ((size_t)Bb * Tt * Cc)

__device__ __forceinline__ float b2f(short s) {
  unsigned int x = ((unsigned int)(unsigned short)s) << 16;
  return __builtin_bit_cast(float, x);
}
__device__ __forceinline__ short f2b(float f) {
  unsigned int x = __builtin_bit_cast(unsigned int, f);
  x += 0x7fffu + ((x >> 16) & 1u);   // round-to-nearest-even
  return (short)(x >> 16);
}

// Async global->LDS DMA, 16B per lane. LDS dest is wave-uniform base +
// lane*16 [m104/m108]; global src is per-lane [m173/m201].
__device__ __forceinline__ void gload16(const void* g, void* l) {
  __builtin_amdgcn_global_load_lds(
      (const __attribute__((address_space(1))) void*)g,
      (__attribute__((address_space(3))) void*)l, 16, 0, 0);
}

// ---------------------------------------------------------------------------
// GEMM: C[m,n] = epilogue( sum_k A[m,k] * B[n,k] )   (B row-major N x K, bf16)
// MODE 0: A fp32 (z-sel Av/Av2),     C bf16, +bias[z*N+n]          (pointwise)
// MODE 1: A bf16 dir-sel, B dir-sel, C bf16 dir-sel                (VWT = W3*V)
// MODE 2: A bf16 dir-sel, B dir-sel, C fp32 = acc/sum + b3 + x     (PV+out)
// MODE 4: scores fused: C=exp(val*scale) -> E (bf16) AND E^T, plus atomic
//         per-row / per-col exp-sum accumulation (softmax denominators).
// Staging: global_load_lds dwordx4. LDS slot map (ROW-major chunks, per-row
// XOR): slot(m,kc) = m*8 + (kc ^ (m&7)).  DMA writes slots linearly; slot d
// maps to source row d>>3, k-chunk (d&7)^(row&7) -> 8 consecutive lanes read
// a PERMUTATION of one aligned 128B row segment (fully coalesced; fixes R6's
// 4KB-stride gather).  ds_read for (ma,kcr) at ma*8+(kcr^(ma&7)): within each
// 8-lane b128 service group banks 4*(kcr^(ma&7)) cover all 8 groups ->
// conflict-free (same as verified R2-R5 layout).
// 128x128 tile, BK=64, 4 waves 2x2, wave tile 64x64 via 4x4 MFMA 16x16x32.
// XCD swizzle (gy%8==0 only): each XCD owns a contiguous y-chunk.
// ---------------------------------------------------------------------------
template<int MODE>
__global__ __launch_bounds__(256, 2)
void gemm_bt(const void* __restrict__ Av, const void* __restrict__ Av2,
             const void* __restrict__ Bv, const void* __restrict__ Bv2,
             void* __restrict__ Cv, void* __restrict__ Cv2,
             const float* __restrict__ bias,
             const float* __restrict__ resid, const float* __restrict__ resid2,
             short* __restrict__ ET, float* __restrict__ sumR, float* __restrict__ sumC,
             int M, int N, int K,
             long long sA, long long sB, long long sC, float scale)
{
  __shared__ __align__(16) short ldsA[8 * 128 * 8];
  __shared__ __align__(16) short ldsB[8 * 128 * 8];
  const int tid  = threadIdx.x;
  const int lane = tid & 63;

  // ---- bijective XCD swizzle (active when gridDim.y % 8 == 0) ----
  int bxi = blockIdx.x, byi = blockIdx.y, bzi = blockIdx.z;
  const int gx = gridDim.x, gy = gridDim.y;
  if ((gy & 7) == 0) {
    int l = bxi + gx * (byi + gy * bzi);
    const int xcd = l & 7;
    int loc = l >> 3;
    const int ych = gy >> 3;
    bxi = loc % gx;  loc /= gx;
    byi = xcd * ych + (loc % ych);
    bzi = loc / ych;
  }

  const int bm = byi * 128;
  const int bn = bxi * 128;
  int dir = 0, zz = bzi;
  if constexpr (MODE == 1 || MODE == 2) { dir = bzi >> 3; zz = bzi & 7; }
  const long long zoA = (long long)zz * sA;
  const long long zoB = (long long)zz * sB;
  const long long zoC = (long long)zz * sC;
  const void* Ause = Av;
  const void* Buse = Bv;
  void* Cuse = Cv;
  if constexpr (MODE == 0) {
    if (zz) Ause = Av2;
  }
  if constexpr (MODE == 1 || MODE == 2) {
    if (dir) { Ause = Av2; Buse = Bv2; Cuse = Cv2; }
  }

  const int wv = tid >> 6;
  const int wm = (wv >> 1) << 6;
  const int wn = (wv & 1) << 6;
  const int wvb = wv << 6;                   // wave chunk base for DMA staging

  f32x4 zero4 = {0.f, 0.f, 0.f, 0.f};
  f32x4 acc[4][4];
#pragma unroll
  for (int i = 0; i < 4; ++i)
#pragma unroll
    for (int j = 0; j < 4; ++j)
      acc[i][j] = zero4;

  const int sm  = tid >> 3;  // 0..31  (MODE0 fp32-A staging)
  const int skc = tid & 7;   // 0..7

  for (int k0 = 0; k0 < K; k0 += 64) {
    if constexpr (MODE == 0) {
      // fp32 A: reg-staged convert + ds_write at slot m*8+(kc^(m&7))
#pragma unroll
      for (int r = 0; r < 4; ++r) {
        const int m = r * 32 + sm;
        const float* ap = (const float*)Ause + zoA + (size_t)(bm + m) * K + k0 + skc * 8;
        float4 f0 = *(const float4*)ap;
        float4 f1 = *(const float4*)(ap + 4);
        short8 av;
        av[0] = f2b(f0.x); av[1] = f2b(f0.y); av[2] = f2b(f0.z); av[3] = f2b(f0.w);
        av[4] = f2b(f1.x); av[5] = f2b(f1.y); av[6] = f2b(f1.z); av[7] = f2b(f1.w);
        *(short8*)&ldsA[((m << 3) + (skc ^ (m & 7))) << 3] = av;
      }
      // bf16 B: DMA, coalesced (8 lanes = one 128B row segment, permuted)
#pragma unroll
      for (int q = 0; q < 4; ++q) {
        const int d  = q * 256 + tid;
        const int mm = d >> 3;
        const int kc = (d & 7) ^ (mm & 7);
        gload16((const short*)Buse + zoB + (size_t)(bn + mm) * K + k0 + kc * 8,
                &ldsB[(size_t)(q * 256 + wvb) * 8]);
      }
    } else {
#pragma unroll
      for (int q = 0; q < 4; ++q) {
        const int d  = q * 256 + tid;
        const int mm = d >> 3;
        const int kc = (d & 7) ^ (mm & 7);
        const size_t ko = (size_t)k0 + kc * 8;
        gload16((const short*)Ause + zoA + (size_t)(bm + mm) * K + ko,
                &ldsA[(size_t)(q * 256 + wvb) * 8]);
        gload16((const short*)Buse + zoB + (size_t)(bn + mm) * K + ko,
                &ldsB[(size_t)(q * 256 + wvb) * 8]);
      }
    }
    __syncthreads();
#pragma unroll
    for (int kk = 0; kk < 2; ++kk) {
      const int kcr = (kk << 2) + (lane >> 4);
      short8 af[4], bfv[4];
#pragma unroll
      for (int i = 0; i < 4; ++i) {
        const int ma = wm + i * 16 + (lane & 15);
        const int nb = wn + i * 16 + (lane & 15);
        af[i]  = *(const short8*)&ldsA[((ma << 3) + (kcr ^ (ma & 7))) << 3];
        bfv[i] = *(const short8*)&ldsB[((nb << 3) + (kcr ^ (nb & 7))) << 3];
      }
#pragma unroll
      for (int i = 0; i < 4; ++i)
#pragma unroll
        for (int j = 0; j < 4; ++j)
          acc[i][j] = __builtin_amdgcn_mfma_f32_16x16x32_bf16(af[i], bfv[j], acc[i][j], 0, 0, 0);
    }
    __syncthreads();
  }

  // C/D layout: col = lane&15, row = (lane>>4)*4 + reg  [measured m89/m91]
  if constexpr (MODE == 4) {
    // ---- exp transform (max-free softmax numerator) ----
#pragma unroll
    for (int i = 0; i < 4; ++i)
#pragma unroll
      for (int j = 0; j < 4; ++j)
#pragma unroll
        for (int r = 0; r < 4; ++r)
          acc[i][j][r] = __expf(acc[i][j][r] * scale);

    // ---- write E (row-major) and E^T ----
#pragma unroll
    for (int i = 0; i < 4; ++i) {
      const int row0 = bm + wm + i * 16 + ((lane >> 4) << 2);
#pragma unroll
      for (int j = 0; j < 4; ++j) {
        const int n = bn + wn + j * 16 + (lane & 15);
        short4v t;
#pragma unroll
        for (int r = 0; r < 4; ++r) t[r] = f2b(acc[i][j][r]);
#pragma unroll
        for (int r = 0; r < 4; ++r)
          ((short*)Cv)[zoC + (size_t)(row0 + r) * N + n] = t[r];
        *(short4v*)(ET + zoC + (size_t)n * M + row0) = t;
      }
    }
    // ---- row sums (dir0 denominators) ----
#pragma unroll
    for (int i = 0; i < 4; ++i) {
      const int row0 = bm + wm + i * 16 + ((lane >> 4) << 2);
#pragma unroll
      for (int r = 0; r < 4; ++r) {
        float p = acc[i][0][r] + acc[i][1][r] + acc[i][2][r] + acc[i][3][r];
#pragma unroll
        for (int o = 1; o < 16; o <<= 1) p += __shfl_xor(p, o, 64);
        if ((lane & 15) == 0)
          unsafeAtomicAdd(&sumR[(size_t)zz * M + row0 + r], p);
      }
    }
    // ---- col sums (dir1 denominators) ----
#pragma unroll
    for (int j = 0; j < 4; ++j) {
      const int n = bn + wn + j * 16 + (lane & 15);
      float q = 0.f;
#pragma unroll
      for (int i = 0; i < 4; ++i)
#pragma unroll
        for (int r = 0; r < 4; ++r) q += acc[i][j][r];
      q += __shfl_xor(q, 16, 64);
      q += __shfl_xor(q, 32, 64);
      if (lane < 16)
        unsafeAtomicAdd(&sumC[(size_t)zz * N + n], q);
    }
  } else if constexpr (MODE == 2) {
    const float* sums = dir ? sumC : sumR;
    const float* xr   = dir ? resid2 : resid;
#pragma unroll
    for (int i = 0; i < 4; ++i) {
      const int row0 = bm + wm + i * 16 + ((lane >> 4) << 2);
#pragma unroll
      for (int r = 0; r < 4; ++r) {
        const float iv = 1.0f / sums[(size_t)zz * M + row0 + r];
#pragma unroll
        for (int j = 0; j < 4; ++j) {
          const int n = bn + wn + j * 16 + (lane & 15);
          const size_t off = zoC + (size_t)(row0 + r) * N + n;
          ((float*)Cuse)[off] = acc[i][j][r] * iv + bias[dir * N + n] + xr[off];
        }
      }
    }
  } else {
#pragma unroll
    for (int i = 0; i < 4; ++i) {
      const int row0 = bm + wm + i * 16 + ((lane >> 4) << 2);
#pragma unroll
      for (int j = 0; j < 4; ++j) {
        const int n = bn + wn + j * 16 + (lane & 15);
        float badd = 0.f;
        if (MODE == 0) badd = bias[(size_t)zz * N + n];
#pragma unroll
        for (int r = 0; r < 4; ++r) {
          float val = acc[i][j][r];
          if (MODE == 0) val += badd;
          ((short*)Cuse)[zoC + (size_t)(row0 + r) * N + n] = f2b(val);
        }
      }
    }
  }
  (void)resid; (void)resid2; (void)ET; (void)sumR; (void)sumC;
  (void)bias; (void)scale; (void)Cuse; (void)M;
}

// ---------------------------------------------------------------------------
// One-shot weight/bias packing + softmax-denominator zeroing.
// Wl=[lp1_w1;lp2_w1], Wr=[rp1_w1;rp2_w1], W3l|W3r, BL=[lp1_b1;lp2_b1], BR,
// B3=[lp3_b;rp3_b], SUM = sumR(16384) ++ sumC(16384) zeroed.
// ---------------------------------------------------------------------------
__global__ __launch_bounds__(256)
void pack_all(const float* __restrict__ lw1a, const float* __restrict__ lw1b,
              const float* __restrict__ rw1a, const float* __restrict__ rw1b,
              const float* __restrict__ w3lf, const float* __restrict__ w3rf,
              const float* __restrict__ lb1a, const float* __restrict__ lb1b,
              const float* __restrict__ rb1a, const float* __restrict__ rb1b,
              const float* __restrict__ b3l, const float* __restrict__ b3r,
              short* __restrict__ Wl, short* __restrict__ Wr,
              short* __restrict__ W3l, short* __restrict__ W3r,
              float* __restrict__ BL, float* __restrict__ BR,
              float* __restrict__ B3, float* __restrict__ SUM)
{
  const int i = blockIdx.x * 256 + threadIdx.x;
  if (i < 524288) {
    Wl[i] = f2b(i < 262144 ? lw1a[i] : lw1b[i - 262144]);
  } else if (i < 1048576) {
    const int j = i - 524288;
    Wr[j] = f2b(j < 262144 ? rw1a[j] : rw1b[j - 262144]);
  } else if (i < 1310720) {
    W3l[i - 1048576] = f2b(w3lf[i - 1048576]);
  } else if (i < 1572864) {
    W3r[i - 1310720] = f2b(w3rf[i - 1310720]);
  } else if (i < 1573888) {
    const int j = i - 1572864;
    BL[j] = j < 512 ? lb1a[j] : lb1b[j - 512];
  } else if (i < 1574912) {
    const int j = i - 1573888;
    BR[j] = j < 512 ? rb1a[j] : rb1b[j - 512];
  } else if (i < 1575936) {
    const int j = i - 1574912;
    B3[j] = j < 512 ? b3l[j] : b3r[j - 512];
  } else if (i < 1608704) {
    SUM[i - 1575936] = 0.f;
  }
}

// ---------------------------------------------------------------------------
// Depthwise conv k=3 pad=1 over T; 4 outputs in one launch (blockIdx.y):
//   y=0: H_l cols[0,512)   w=lp1 -> Ql   y=1: H_r cols[0,512)   w=rp1 -> Qr
//   y=2: H_l cols[512,1024) w=lp2 -> Vl  y=3: H_r cols[512,1024) w=rp2 -> Vr
// H row stride 1024 (fused proj output). All outputs row-major (B*T, 512).
// ---------------------------------------------------------------------------
__global__ __launch_bounds__(256)
void dw_kernel(const short* __restrict__ H, long long hStride,
               const float* __restrict__ w2a, const float* __restrict__ w2b,
               const float* __restrict__ w2c, const float* __restrict__ w2d,
               const float* __restrict__ b2a, const float* __restrict__ b2b,
               const float* __restrict__ b2c, const float* __restrict__ b2d,
               short* __restrict__ out)
{
  const int y = blockIdx.y;
  const short* Hd = H + (size_t)(y & 1) * hStride;
  const float* w2 = (y == 0) ? w2a : (y == 1) ? w2b : (y == 2) ? w2c : w2d;
  const float* b2 = (y == 0) ? b2a : (y == 1) ? b2b : (y == 2) ? b2c : b2d;
  const int colOff = (y & 2) ? 512 : 0;
  short* outd = out + (size_t)y * SZE;

  const int idx = blockIdx.x * 256 + threadIdx.x;   // over B*T*512/8
  const int c8 = idx & 63;
  const int bt = idx >> 6;
  const int t  = bt & (Tt - 1);
  const int c  = c8 << 3;
  const short* base = Hd + (size_t)bt * 1024 + colOff + c;
  short8 zv = {0, 0, 0, 0, 0, 0, 0, 0};
  short8 hm = zv, hp = zv;
  short8 h0 = *(const short8*)base;
  if (t > 0)      hm = *(const short8*)(base - 1024);
  if (t < Tt - 1) hp = *(const short8*)(base + 1024);
  short8 o;
#pragma unroll
  for (int j = 0; j < 8; ++j) {
    const int cj = c + j;
    float val = b2f(hm[j]) * w2[cj * 3 + 0]
              + b2f(h0[j]) * w2[cj * 3 + 1]
              + b2f(hp[j]) * w2[cj * 3 + 2]
              + b2[cj];
    o[j] = f2b(val);
  }
  *(short8*)(outd + (size_t)bt * Cc + c) = o;
}

// ---------------------------------------------------------------------------
extern "C" void kernel_launch(void* const* d_in, const int* in_sizes, int n_in,
                              void* d_out, int out_size, void* d_ws, size_t ws_size,
                              hipStream_t stream)
{
  const float* x_l    = (const float*)d_in[0];
  const float* x_r    = (const float*)d_in[1];
  const float* lp1_w1 = (const float*)d_in[2];
  const float* lp1_b1 = (const float*)d_in[3];
  const float* lp1_w2 = (const float*)d_in[4];
  const float* lp1_b2 = (const float*)d_in[5];
  const float* rp1_w1 = (const float*)d_in[6];
  const float* rp1_b1 = (const float*)d_in[7];
  const float* rp1_w2 = (const float*)d_in[8];
  const float* rp1_b2 = (const float*)d_in[9];
  const float* lp2_w1 = (const float*)d_in[10];
  const float* lp2_b1 = (const float*)d_in[11];
  const float* lp2_w2 = (const float*)d_in[12];
  const float* lp2_b2 = (const float*)d_in[13];
  const float* rp2_w1 = (const float*)d_in[14];
  const float* rp2_b1 = (const float*)d_in[15];
  const float* rp2_w2 = (const float*)d_in[16];
  const float* rp2_b2 = (const float*)d_in[17];
  const float* lp3_w  = (const float*)d_in[18];
  const float* lp3_b  = (const float*)d_in[19];
  const float* rp3_w  = (const float*)d_in[20];
  const float* rp3_b  = (const float*)d_in[21];

  short* ws = (short*)d_ws;
  const size_t SZ = SZE;                     // 8,388,608 bf16 elems (16.78 MB)
  short* Ql   = ws;                          // slot0; later VWT0
  short* Qr   = ws + SZ;                     // slot1; later VWT1
  short* Vl   = ws + 2 * SZ;                 // slot2
  short* Vr   = ws + 3 * SZ;                 // slot3
  short* E    = ws + 4 * SZ;                 // [4,8)SZ; H aliases this region
  short* ETb  = ws + 8 * SZ;                 // [8,12)SZ
  short* H    = E;
  short* VWT0 = Ql;                          // Q dead after QK^T
  short* VWT1 = Qr;

  const size_t W_PAIR = 524288, W_SING = 262144;
  short* Wl  = ws + 12 * SZ;
  short* Wr  = Wl + W_PAIR;
  short* W3l = Wr + W_PAIR;
  short* W3r = W3l + W_SING;
  float* BL  = (float*)(W3r + W_SING);
  float* BR  = BL + 1024;
  float* B3  = BR + 1024;
  float* SUMR = B3 + 1024;                   // 16384 floats (dir0 row sums)
  float* SUMC = SUMR + 16384;                // 16384 floats (dir1 = col sums)

  const float scale = 0.04419417382415922f;  // 512^-0.5
  const int MT = Bb * Tt;                    // 16384
  const long long sQ = (long long)Tt * Cc;   // 1,048,576
  const long long sS = (long long)Tt * Tt;   // 4,194,304

  dim3 blk(256);

  // ---- phase 0: pack weights + zero softmax denominators ----
  pack_all<<<6284, blk, 0, stream>>>(lp1_w1, lp2_w1, rp1_w1, rp2_w1, lp3_w, rp3_w,
                                     lp1_b1, lp2_b1, rp1_b1, rp2_b1, lp3_b, rp3_b,
                                     Wl, Wr, W3l, W3r, BL, BR, B3, SUMR);

  // ---- phase 1: fused pointwise proj (N=1024, both dirs z=2) -> dw convs ----
  gemm_bt<0><<<dim3(8, 128, 2), blk, 0, stream>>>(
      x_l, x_r, Wl, nullptr, H, nullptr, BL, nullptr, nullptr,
      nullptr, nullptr, nullptr,
      MT, 1024, Cc, 0, (long long)W_PAIR, (long long)(2 * SZ), 1.f);
  dw_kernel<<<dim3(4096, 4), blk, 0, stream>>>(
      H, (long long)(2 * SZ),
      lp1_w2, rp1_w2, lp2_w2, rp2_w2,
      lp1_b2, rp1_b2, lp2_b2, rp2_b2, Ql);

  // ---- phase 2a: single fused QK^T -> exp -> E, E^T, row/col sums ----
  gemm_bt<4><<<dim3(Tt / 128, Tt / 128, Bb), blk, 0, stream>>>(
      Ql, nullptr, Qr, nullptr, E, nullptr, nullptr, nullptr, nullptr,
      ETb, SUMR, SUMC,
      Tt, Tt, Cc, sQ, sQ, sS, scale);

  // ---- phase 2b: VWT[d,s] = sum_c W3[d,c] V[s,c]  (z=16: dir,batch) ----
  // dir0 uses V_r (feeds out_l), dir1 uses V_l. Overwrites dead Q slots.
  gemm_bt<1><<<dim3(Tt / 128, 4, 2 * Bb), blk, 0, stream>>>(
      W3l, W3r, Vr, Vl, VWT0, VWT1, nullptr, nullptr, nullptr,
      nullptr, nullptr, nullptr,
      512, Tt, Cc, 0, sQ, (long long)(512 * Tt), 1.f);

  // ---- phase 3: PV + epilogue = out (z=16): C = E*VWT/sum + b3 + x ----
  gemm_bt<2><<<dim3(Cc / 128, Tt / 128, 2 * Bb), blk, 0, stream>>>(
      E, ETb, VWT0, VWT1, d_out, (float*)d_out + SZ, B3, x_l, x_r,
      nullptr, SUMR, SUMC,
      Tt, Cc, Tt, sS, (long long)(512 * Tt), sQ, 1.f);

  (void)in_sizes; (void)n_in; (void)out_size; (void)ws_size;
}